// Round 18
// baseline (31.600 us; speedup 1.0000x reference)
//
#include <hip/hip_runtime.h>
#include <stdint.h>

#define BB 2
#define DD 64
#define HH 128
#define WW 128
#define NVOX (DD*HH*WW)        // 2^20 per batch
#define TOTAL (BB*NVOX)        // 2097152
#define HBINS 36868            // > max finite dsq (36227)
#define NWORDS (TOTAL/16)      // 131072 uint16 mask words per volume
#define NSLOT 16               // hot-flush shadow slots per g
#define HOTN (4*NSLOT*4)
#define ZEROINTS (4*HBINS + HOTN + 4 + 1)   // bigh || hot || maxv || done
#define EGRID (BB*DD*2*2)      // 512 blocks: (slice, dir, y-half)

__device__ __forceinline__ int aload(const int* p)
{
    return __hip_atomic_load(p, __ATOMIC_RELAXED, __HIP_MEMORY_SCOPE_AGENT);
}

// ---------- bitpack: float>0.5 masks -> 16-voxel uint16 words; zero ints ---
__global__ __launch_bounds__(256)
void bitpack_kernel(const float* __restrict__ pred, const float* __restrict__ targ,
                    uint16_t* __restrict__ pb, uint16_t* __restrict__ tb,
                    int* __restrict__ zint)
{
    int gt = blockIdx.x * 256 + threadIdx.x;       // 0..NWORDS-1
    for (int t = gt; t < ZEROINTS; t += NWORDS) zint[t] = 0;

    const float4* p4 = (const float4*)pred + gt * 4;
    const float4* t4 = (const float4*)targ + gt * 4;
    uint32_t pbits = 0, tbits = 0;
    #pragma unroll
    for (int j = 0; j < 4; ++j) {
        float4 v = p4[j];
        pbits |= ((uint32_t)(v.x > 0.5f) | (uint32_t)(v.y > 0.5f) << 1 |
                  (uint32_t)(v.z > 0.5f) << 2 | (uint32_t)(v.w > 0.5f) << 3) << (4 * j);
        float4 w = t4[j];
        tbits |= ((uint32_t)(w.x > 0.5f) | (uint32_t)(w.y > 0.5f) << 1 |
                  (uint32_t)(w.z > 0.5f) << 2 | (uint32_t)(w.w > 0.5f) << 3) << (4 * j);
    }
    pb[gt] = (uint16_t)pbits;
    tb[gt] = (uint16_t)tbits;
}

// ---------- exact slow path (executed ~never; correctness fallback) --------
__device__ __forceinline__ int getbit(const uint16_t* __restrict__ M,
                                      int b, int z, int y, int x)
{
    return (M[(((size_t)(b * DD + z)) << 10) + (y << 3) + (x >> 4)] >> (x & 15)) & 1;
}

__device__ bool is_edge(const uint16_t* __restrict__ M, int b, int z, int y, int x)
{
    if (!getbit(M, b, z, y, x)) return false;
    if (x == 0 || x == WW-1 || y == 0 || y == HH-1 || z == 0 || z == DD-1) return true;
    int er = getbit(M,b,z,y,x-1) & getbit(M,b,z,y,x+1) &
             getbit(M,b,z,y-1,x) & getbit(M,b,z,y+1,x) &
             getbit(M,b,z-1,y,x) & getbit(M,b,z+1,y,x);
    return !er;
}

__device__ int slow_d2(const uint16_t* __restrict__ M, int b, int z, int y, int x)
{
    int best = 0x7FFFFFFF;
    for (int r = 2; r <= 127; ++r) {
        if (best <= r * r) break;
        for (int dz = -r; dz <= r; ++dz) {
            int zz = z + dz; if (zz < 0 || zz >= DD) continue;
            for (int dy = -r; dy <= r; ++dy) {
                int yy = y + dy; if (yy < 0 || yy >= HH) continue;
                int cheb = max(abs(dz), abs(dy));
                if (cheb == r) {
                    for (int dx = -r; dx <= r; ++dx) {
                        int xx = x + dx; if (xx < 0 || xx >= WW) continue;
                        if (is_edge(M, b, zz, yy, xx))
                            best = min(best, dz*dz + dy*dy + dx*dx);
                    }
                } else {
                    for (int t2 = 0; t2 < 2; ++t2) {
                        int dx = t2 ? r : -r;
                        int xx = x + dx; if (xx < 0 || xx >= WW) continue;
                        if (is_edge(M, b, zz, yy, xx))
                            best = min(best, dz*dz + dy*dy + dx*dx);
                    }
                }
            }
        }
    }
    return best;
}

// ---------- edges + word-parallel r<=1 distance + histogram + tail ---------
// Block = (slice bz, dir, y-half). 512 threads, one eval word each.
__global__ __launch_bounds__(512)
void edge_dist_hist(const uint16_t* __restrict__ pb, const uint16_t* __restrict__ tb,
                    int* __restrict__ bigh, int* __restrict__ hot,
                    int* __restrict__ maxv, int* __restrict__ done,
                    float* __restrict__ out)
{
    __shared__ __align__(16) uint16_t ownm[3][66][8];   // own mask, rows y0-1..y0+64
    __shared__ __align__(16) uint16_t othm[5][68][8];   // oth mask, rows y0-2..y0+65
    __shared__ __align__(16) uint16_t tedge[3][66][8];  // oth edge, rows y0-1..y0+64
    __shared__ int lh[4];
    __shared__ int lastflag;
    int gid = blockIdx.x, tid = threadIdx.x;
    int dir = gid & 1;
    int yh  = (gid >> 1) & 1;
    int bz  = gid >> 2;                  // b*DD + z
    int b   = bz >> 6, z = bz & (DD - 1);
    int y0  = yh * 64;
    const uint16_t* own = dir ? tb : pb;   // dir0: E = pred edges
    const uint16_t* oth = dir ? pb : tb;   // dir0: distances to targ edges
    int lane = tid & 63;

    // ---- halo-staged loads (out-of-range rows/slices zeroed) --------------
    if (tid < 3 * 66) {
        int s = tid / 66, rr = tid % 66;
        int gz = z - 1 + s, gy = y0 - 1 + rr;
        uint4 v = make_uint4(0, 0, 0, 0);
        if (gz >= 0 && gz < DD && gy >= 0 && gy < HH)
            v = *(const uint4*)(own + (((size_t)(b * DD + gz)) << 10) + (gy << 3));
        *(uint4*)&ownm[s][rr][0] = v;
    }
    if (tid < 5 * 68) {
        int s = tid / 68, rr = tid % 68;
        int gz = z - 2 + s, gy = y0 - 2 + rr;
        uint4 v = make_uint4(0, 0, 0, 0);
        if (gz >= 0 && gz < DD && gy >= 0 && gy < HH)
            v = *(const uint4*)(oth + (((size_t)(b * DD + gz)) << 10) + (gy << 3));
        *(uint4*)&othm[s][rr][0] = v;
    }
    if (tid < 4) lh[tid] = 0;
    __syncthreads();

    // ---- phase A: oth edge words, slices z-1..z+1, rows y0-1..y0+64 -------
    for (int i = tid; i < 3 * 66 * 8; i += 512) {
        int s = i / 528, r2 = i % 528, t = r2 >> 3, wx = r2 & 7;
        uint32_t c = othm[s + 1][t + 1][wx];
        uint32_t l = wx > 0 ? othm[s + 1][t + 1][wx - 1] : 0;
        uint32_t r = wx < 7 ? othm[s + 1][t + 1][wx + 1] : 0;
        uint32_t ext = (l >> 15) | (c << 1) | ((r & 1u) << 17);
        uint32_t m = (ext >> 1) & 0xFFFFu, L = ext & 0xFFFFu, R = (ext >> 2) & 0xFFFFu;
        uint32_t ym = othm[s + 1][t][wx];
        uint32_t yp = othm[s + 1][t + 2][wx];
        uint32_t zm = othm[s][t + 1][wx], zp = othm[s + 2][t + 1][wx];
        uint32_t er = m & L & R & ym & yp & zm & zp;
        tedge[s][t][wx] = (uint16_t)(m & ~er);
    }

    // ---- E: own edge word for this thread's eval word ---------------------
    int rr = tid >> 3, wx = tid & 7;     // eval row rr (gy = y0+rr), word wx
    uint32_t E;
    {
        uint32_t c = ownm[1][rr + 1][wx];
        uint32_t l = wx > 0 ? ownm[1][rr + 1][wx - 1] : 0;
        uint32_t r = wx < 7 ? ownm[1][rr + 1][wx + 1] : 0;
        uint32_t ext = (l >> 15) | (c << 1) | ((r & 1u) << 17);
        uint32_t m = (ext >> 1) & 0xFFFFu, L = ext & 0xFFFFu, R = (ext >> 2) & 0xFFFFu;
        uint32_t ym = ownm[1][rr][wx], yp = ownm[1][rr + 2][wx];
        uint32_t zm = ownm[0][rr + 1][wx], zp = ownm[2][rr + 1][wx];
        E = m & ~(m & L & R & ym & yp & zm & zp);
    }
    __syncthreads();   // tedge ready

    // ---- phase B: M0..M3 = has oth-edge at d^2 = 0/1/2/3 ------------------
    uint32_t M0 = 0, M1 = 0, M2 = 0, M3 = 0;
    #pragma unroll
    for (int dzi = 0; dzi < 3; ++dzi) {
        #pragma unroll
        for (int dyy = -1; dyy <= 1; ++dyy) {
            int rt = rr + 1 + dyy;
            uint32_t c = tedge[dzi][rt][wx];
            uint32_t l = wx > 0 ? tedge[dzi][rt][wx - 1] : 0;
            uint32_t r = wx < 7 ? tedge[dzi][rt][wx + 1] : 0;
            uint32_t ext = (l >> 15) | (c << 1) | ((r & 1u) << 17);
            uint32_t s0 = (ext >> 1) & 0xFFFFu;                      // dx = 0
            uint32_t s1 = (ext & 0xFFFFu) | ((ext >> 2) & 0xFFFFu);  // dx = +-1
            int a = (dzi == 1 ? 0 : 1) + (dyy == 0 ? 0 : 1);
            if (a == 0)      { M0 |= s0; M1 |= s1; }
            else if (a == 1) { M1 |= s0; M2 |= s1; }
            else             { M2 |= s0; M3 |= s1; }
        }
    }

    uint32_t rem = E;
    int c0 = __popc(rem & M0); rem &= ~M0;
    int c1 = __popc(rem & M1); rem &= ~M1;
    int c2 = __popc(rem & M2); rem &= ~M2;
    int c3 = __popc(rem & M3); rem &= ~M3;

    int g = b * 2 + dir;
    int gy = y0 + rr;

    // slow path for residual bits (expected ~0 voxels total)
    while (rem) {
        int i = __builtin_ctz(rem); rem &= rem - 1;
        int d2 = slow_d2(oth, b, z, gy, wx * 16 + i);
        if (d2 >= HBINS) d2 = HBINS - 1;
        atomicAdd(&bigh[(size_t)g * HBINS + d2], 1);
        atomicMax(&maxv[g], d2);
    }

    // wave reduce the 4 hot counters, then one LDS atomic per wave
    #pragma unroll
    for (int o = 1; o < 64; o <<= 1) {
        c0 += __shfl_xor(c0, o, 64);
        c1 += __shfl_xor(c1, o, 64);
        c2 += __shfl_xor(c2, o, 64);
        c3 += __shfl_xor(c3, o, 64);
    }
    if (lane == 0) {
        if (c0) atomicAdd(&lh[0], c0);
        if (c1) atomicAdd(&lh[1], c1);
        if (c2) atomicAdd(&lh[2], c2);
        if (c3) atomicAdd(&lh[3], c3);
    }
    __syncthreads();
    if (tid < 4) {
        int v = lh[tid];
        int slot = (gid >> 1) & (NSLOT - 1);   // spread flush across 16 shadows
        if (v) atomicAdd(&hot[(g * NSLOT + slot) * 4 + tid], v);
    }
    // drain this block's flush atomics (syncthreads implies vmcnt(0) per wave)
    __syncthreads();
    if (tid == 0) {
        int old = __hip_atomic_fetch_add(done, 1, __ATOMIC_RELAXED,
                                         __HIP_MEMORY_SCOPE_AGENT);
        lastflag = (old == EGRID - 1);
    }
    __syncthreads();
    if (!lastflag) return;

    // ------------- last block only: percentile (wave w handles g=w) -------
    if (tid >= 256) return;
    {
        int gg = tid >> 6;
        const int* gbig = bigh + (size_t)gg * HBINS;
        int mb = aload(&maxv[gg]);
        if (mb < 3) mb = 3;
        if (mb >= HBINS) mb = HBINS - 1;

        // pass 1: total count n over bins [0..mb]
        int n = 0;
        for (int cc = 0; cc <= mb; cc += 64) {
            int bin = cc + lane;
            int cnt = 0;
            if (bin <= mb) {
                cnt = aload(&gbig[bin]);
                if (bin < 4) {
                    #pragma unroll
                    for (int s = 0; s < NSLOT; ++s)
                        cnt += aload(&hot[(gg * NSLOT + s) * 4 + bin]);
                }
            }
            #pragma unroll
            for (int o = 1; o < 64; o <<= 1) cnt += __shfl_xor(cnt, o, 64);
            n += cnt;
        }

        float pos = 0.95f * (float)(n - 1);
        float fpos = floorf(pos);
        int lo = (int)fpos;
        int nm1 = n - 1; if (nm1 < 0) nm1 = 0;
        if (lo < 0) lo = 0;
        if (lo > nm1) lo = nm1;
        int hi = lo + 1; if (hi > nm1) hi = nm1;
        float frac = pos - fpos;

        // pass 2: rank select
        int basec = 0, sel0 = 0, sel1 = 0;
        bool f0 = false, f1 = false;
        for (int cc = 0; cc <= mb && !(f0 && f1); cc += 64) {
            int bin = cc + lane;
            int cnt = 0;
            if (bin <= mb) {
                cnt = aload(&gbig[bin]);
                if (bin < 4) {
                    #pragma unroll
                    for (int s = 0; s < NSLOT; ++s)
                        cnt += aload(&hot[(gg * NSLOT + s) * 4 + bin]);
                }
            }
            int inc = cnt;
            #pragma unroll
            for (int o = 1; o < 64; o <<= 1) {
                int t = __shfl_up(inc, o, 64);
                if (lane >= o) inc += t;
            }
            int exc = inc - cnt;
            unsigned long long b0 = __ballot(!f0 && lo >= basec + exc && lo < basec + inc);
            if (b0) { sel0 = cc + (__ffsll(b0) - 1); f0 = true; }
            unsigned long long b1 = __ballot(!f1 && hi >= basec + exc && hi < basec + inc);
            if (b1) { sel1 = cc + (__ffsll(b1) - 1); f1 = true; }
            basec += __shfl(inc, 63, 64);
        }
        if (lane == 0) {
            float a = sqrtf((float)sel0);
            float bv = sqrtf((float)sel1);
            float val = a + frac * (bv - a);
            atomicMax((int*)out + (gg >> 1), __float_as_int(val));  // val>=0
        }
    }
}

extern "C" void kernel_launch(void* const* d_in, const int* in_sizes, int n_in,
                              void* d_out, int out_size, void* d_ws, size_t ws_size,
                              hipStream_t stream)
{
    const float* pred = (const float*)d_in[0];
    const float* targ = (const float*)d_in[1];
    float* out = (float*)d_out;

    uint8_t* ws = (uint8_t*)d_ws;
    uint16_t* pb = (uint16_t*)ws;                    // NWORDS u16 (pred mask bits)
    uint16_t* tb = pb + NWORDS;                      // NWORDS u16 (targ mask bits)
    int* bigh    = (int*)(tb + NWORDS);              // 4*HBINS ints (slow path)
    int* hot     = bigh + 4 * HBINS;                 // HOTN ints (d^2 = 0..3)
    int* maxv    = hot + HOTN;                       // 4 ints
    int* done    = maxv + 4;                         // 1 int
    // bitpack zeroes [bigh .. bigh+ZEROINTS) = bigh||hot||maxv||done

    bitpack_kernel<<<NWORDS/256, 256, 0, stream>>>(pred, targ, pb, tb, bigh);
    edge_dist_hist<<<EGRID, 512, 0, stream>>>(pb, tb, bigh, hot, maxv, done, out);
}

// Round 19
// 27.708 us; speedup vs baseline: 1.1405x; 1.1405x over previous
//
#include <hip/hip_runtime.h>
#include <stdint.h>

#define BB 2
#define DD 64
#define HH 128
#define WW 128
#define NVOX (DD*HH*WW)        // 2^20 per batch
#define TOTAL (BB*NVOX)        // 2097152
#define NWORDS (TOTAL/16)      // 131072 uint16 mask words per volume
#define HOTN (4*8*4)           // 4 g x 8 slots x 4 hot bins
#define ZEROINTS (HOTN + 1 + 1)   // hot || done || listCnt  (130 ints)
#define EGRID (BB*DD*2)        // 256 blocks
#define CAP (1<<20)            // residual list capacity (value entries)
#define MAXD2 36227            // 63^2+127^2+127^2

__device__ __forceinline__ int aload(const int* p)
{
    return __hip_atomic_load(p, __ATOMIC_RELAXED, __HIP_MEMORY_SCOPE_AGENT);
}

// ---------- bitpack: float>0.5 masks -> 16-voxel uint16 words; zero ints ---
__global__ __launch_bounds__(256)
void bitpack_kernel(const float* __restrict__ pred, const float* __restrict__ targ,
                    uint16_t* __restrict__ pb, uint16_t* __restrict__ tb,
                    int* __restrict__ zint)
{
    int gt = blockIdx.x * 256 + threadIdx.x;       // 0..NWORDS-1
    if (gt < ZEROINTS) zint[gt] = 0;

    const float4* p4 = (const float4*)pred + gt * 4;
    const float4* t4 = (const float4*)targ + gt * 4;
    uint32_t pbits = 0, tbits = 0;
    #pragma unroll
    for (int j = 0; j < 4; ++j) {
        float4 v = p4[j];
        pbits |= ((uint32_t)(v.x > 0.5f) | (uint32_t)(v.y > 0.5f) << 1 |
                  (uint32_t)(v.z > 0.5f) << 2 | (uint32_t)(v.w > 0.5f) << 3) << (4 * j);
        float4 w = t4[j];
        tbits |= ((uint32_t)(w.x > 0.5f) | (uint32_t)(w.y > 0.5f) << 1 |
                  (uint32_t)(w.z > 0.5f) << 2 | (uint32_t)(w.w > 0.5f) << 3) << (4 * j);
    }
    pb[gt] = (uint16_t)pbits;
    tb[gt] = (uint16_t)tbits;
}

// ---------- exact slow path (executed ~never; correctness fallback) --------
__device__ __forceinline__ int getbit(const uint16_t* __restrict__ M,
                                      int b, int z, int y, int x)
{
    return (M[(((size_t)(b * DD + z)) << 10) + (y << 3) + (x >> 4)] >> (x & 15)) & 1;
}

__device__ bool is_edge(const uint16_t* __restrict__ M, int b, int z, int y, int x)
{
    if (!getbit(M, b, z, y, x)) return false;
    if (x == 0 || x == WW-1 || y == 0 || y == HH-1 || z == 0 || z == DD-1) return true;
    int er = getbit(M,b,z,y,x-1) & getbit(M,b,z,y,x+1) &
             getbit(M,b,z,y-1,x) & getbit(M,b,z,y+1,x) &
             getbit(M,b,z-1,y,x) & getbit(M,b,z+1,y,x);
    return !er;
}

__device__ int slow_d2(const uint16_t* __restrict__ M, int b, int z, int y, int x)
{
    int best = 0x7FFFFFFF;
    for (int r = 2; r <= 127; ++r) {
        if (best <= r * r) break;
        for (int dz = -r; dz <= r; ++dz) {
            int zz = z + dz; if (zz < 0 || zz >= DD) continue;
            for (int dy = -r; dy <= r; ++dy) {
                int yy = y + dy; if (yy < 0 || yy >= HH) continue;
                int cheb = max(abs(dz), abs(dy));
                if (cheb == r) {
                    for (int dx = -r; dx <= r; ++dx) {
                        int xx = x + dx; if (xx < 0 || xx >= WW) continue;
                        if (is_edge(M, b, zz, yy, xx))
                            best = min(best, dz*dz + dy*dy + dx*dx);
                    }
                } else {
                    for (int t2 = 0; t2 < 2; ++t2) {
                        int dx = t2 ? r : -r;
                        int xx = x + dx; if (xx < 0 || xx >= WW) continue;
                        if (is_edge(M, b, zz, yy, xx))
                            best = min(best, dz*dz + dy*dy + dx*dx);
                    }
                }
            }
        }
    }
    return best;
}

// ---------- edges + word-parallel r<=1 distance + histogram + tail ---------
__global__ __launch_bounds__(1024)
void edge_dist_hist(const uint16_t* __restrict__ pb, const uint16_t* __restrict__ tb,
                    int* __restrict__ hot, int* __restrict__ done,
                    int* __restrict__ listCnt, int* __restrict__ list,
                    float* __restrict__ out)
{
    __shared__ uint16_t ownm[3][1024];   // own mask slices  z-1..z+1
    __shared__ uint16_t othm[5][1024];   // other mask slices z-2..z+2
    __shared__ uint16_t tedge[3][1024];  // other EDGE slices z-1..z+1
    __shared__ int lh[4];
    __shared__ int lastflag;
    int gid = blockIdx.x, tid = threadIdx.x;
    int dir = gid & 1;
    int bz  = gid >> 1;
    int b   = bz >> 6, z = bz & (DD - 1);
    const uint16_t* own = dir ? tb : pb;   // dir0: E = pred edges
    const uint16_t* oth = dir ? pb : tb;   // dir0: distances to targ edges

    {   // cooperative load: 8 slices x 1024 words (zero out-of-range slices)
        int s = tid >> 7, off = (tid & 127) * 8;
        int zs = (s < 3) ? z + s - 1 : z + s - 5;
        const uint16_t* src = (s < 3) ? own : oth;
        uint16_t* dst = (s < 3) ? &ownm[s][off] : &othm[s - 3][off];
        if (zs >= 0 && zs < DD)
            *(uint4*)dst = *(const uint4*)(src + (((size_t)(b * DD + zs)) << 10) + off);
        else
            *(uint4*)dst = make_uint4(0, 0, 0, 0);
    }
    if (tid < 4) lh[tid] = 0;
    __syncthreads();

    int w = tid, y = w >> 3, wx = w & 7;

    // phase A: other-surface edge words for dz in {-1,0,1}
    #pragma unroll
    for (int dzi = 0; dzi < 3; ++dzi) {
        uint32_t c = othm[dzi + 1][w];
        uint32_t l = wx > 0 ? othm[dzi + 1][w - 1] : 0;
        uint32_t r = wx < 7 ? othm[dzi + 1][w + 1] : 0;
        uint32_t ext = (l >> 15) | (c << 1) | ((r & 1u) << 17);
        uint32_t m = (ext >> 1) & 0xFFFFu, L = ext & 0xFFFFu, R = (ext >> 2) & 0xFFFFu;
        uint32_t ym = y > 0   ? othm[dzi + 1][w - 8] : 0;
        uint32_t yp = y < 127 ? othm[dzi + 1][w + 8] : 0;
        uint32_t zm = othm[dzi][w], zp = othm[dzi + 2][w];
        uint32_t er = m & L & R & ym & yp & zm & zp;
        tedge[dzi][w] = (uint16_t)(m & ~er);
    }

    // E: own-surface edge word
    uint32_t E;
    {
        uint32_t c = ownm[1][w];
        uint32_t l = wx > 0 ? ownm[1][w - 1] : 0;
        uint32_t r = wx < 7 ? ownm[1][w + 1] : 0;
        uint32_t ext = (l >> 15) | (c << 1) | ((r & 1u) << 17);
        uint32_t m = (ext >> 1) & 0xFFFFu, L = ext & 0xFFFFu, R = (ext >> 2) & 0xFFFFu;
        uint32_t ym = y > 0   ? ownm[1][w - 8] : 0;
        uint32_t yp = y < 127 ? ownm[1][w + 8] : 0;
        uint32_t zm = ownm[0][w], zp = ownm[2][w];
        E = m & ~(m & L & R & ym & yp & zm & zp);
    }
    __syncthreads();   // tedge ready

    // phase B: M0..M3 (has oth-edge at d^2=0/1/2/3) from tedge ext rows
    uint32_t M0 = 0, M1 = 0, M2 = 0, M3 = 0;
    #pragma unroll
    for (int dzi = 0; dzi < 3; ++dzi) {
        #pragma unroll
        for (int dyy = -1; dyy <= 1; ++dyy) {
            int yy = y + dyy;
            uint32_t c = 0, l = 0, r = 0;
            if (yy >= 0 && yy < HH) {
                int w2 = (yy << 3) + wx;
                c = tedge[dzi][w2];
                l = wx > 0 ? tedge[dzi][w2 - 1] : 0;
                r = wx < 7 ? tedge[dzi][w2 + 1] : 0;
            }
            uint32_t ext = (l >> 15) | (c << 1) | ((r & 1u) << 17);
            uint32_t s0 = (ext >> 1) & 0xFFFFu;                      // dx = 0
            uint32_t s1 = (ext & 0xFFFFu) | ((ext >> 2) & 0xFFFFu);  // dx = +-1
            int a = (dzi == 1 ? 0 : 1) + (dyy == 0 ? 0 : 1);
            if (a == 0)      { M0 |= s0; M1 |= s1; }
            else if (a == 1) { M1 |= s0; M2 |= s1; }
            else             { M2 |= s0; M3 |= s1; }
        }
    }

    uint32_t rem = E;
    int c0 = __popc(rem & M0); rem &= ~M0;
    int c1 = __popc(rem & M1); rem &= ~M1;
    int c2 = __popc(rem & M2); rem &= ~M2;
    int c3 = __popc(rem & M3); rem &= ~M3;

    int g = b * 2 + dir;

    // slow path for residual bits (expected ~0 voxels total): append VALUE
    while (rem) {
        int i = __builtin_ctz(rem); rem &= rem - 1;
        int d2 = slow_d2(oth, b, z, y, wx * 16 + i);   // always >= 4
        if (d2 > MAXD2) d2 = MAXD2;
        int pos = atomicAdd(listCnt, 1);
        if (pos < CAP)
            __hip_atomic_store(&list[pos], (g << 16) | d2,
                               __ATOMIC_RELEASE, __HIP_MEMORY_SCOPE_AGENT);
    }

    // wave reduce the 4 hot counters, then one LDS atomic per wave
    int lane = tid & 63;
    #pragma unroll
    for (int o = 1; o < 64; o <<= 1) {
        c0 += __shfl_xor(c0, o, 64);
        c1 += __shfl_xor(c1, o, 64);
        c2 += __shfl_xor(c2, o, 64);
        c3 += __shfl_xor(c3, o, 64);
    }
    if (lane == 0) {
        if (c0) atomicAdd(&lh[0], c0);
        if (c1) atomicAdd(&lh[1], c1);
        if (c2) atomicAdd(&lh[2], c2);
        if (c3) atomicAdd(&lh[3], c3);
    }
    __syncthreads();
    if (tid < 4) {
        int v = lh[tid];
        int slot = bz & 7;             // spread global flush across 8 shadows
        if (v) atomicAdd(&hot[(g * 8 + slot) * 4 + tid], v);
    }
    // drain this block's flush atomics (syncthreads implies vmcnt(0) per wave)
    __syncthreads();
    if (tid == 0) {
        int old = __hip_atomic_fetch_add(done, 1, __ATOMIC_RELAXED,
                                         __HIP_MEMORY_SCOPE_AGENT);
        lastflag = (old == EGRID - 1);
    }
    __syncthreads();
    if (!lastflag) return;

    // ------------- last block only: percentile (wave w handles g=w) -------
    if (tid >= 256) return;
    {
        int gg = tid >> 6;
        int nL = aload(listCnt); if (nL > CAP) nL = CAP;

        // hot totals for this g (lanes 0..3 gather, then broadcast)
        int cb = 0;
        if (lane < 4) {
            #pragma unroll
            for (int s = 0; s < 8; ++s) cb += aload(&hot[(gg * 8 + s) * 4 + lane]);
        }
        int h0 = __shfl(cb, 0, 64), h1 = __shfl(cb, 1, 64);
        int h2 = __shfl(cb, 2, 64), h3 = __shfl(cb, 3, 64);

        // count of this g's list entries (wave-uniform after reduce)
        int cg = 0;
        for (int i = lane; i < nL; i += 64) {
            int e = aload(&list[i]);
            if ((e >> 16) == gg) cg++;
        }
        #pragma unroll
        for (int o = 1; o < 64; o <<= 1) cg += __shfl_xor(cg, o, 64);

        int n = h0 + h1 + h2 + h3 + cg;
        int hotTot = n - cg;

        float pos = 0.95f * (float)(n - 1);
        float fpos = floorf(pos);
        int lo = (int)fpos;
        int nm1 = n - 1; if (nm1 < 0) nm1 = 0;
        if (lo < 0) lo = 0;
        if (lo > nm1) lo = nm1;
        int hi = lo + 1; if (hi > nm1) hi = nm1;
        float frac = pos - fpos;

        int sel[2]; int ranks[2] = {lo, hi};
        #pragma unroll
        for (int ri = 0; ri < 2; ++ri) {
            int r = ranks[ri];
            int v;
            if      (r < h0)               v = 0;
            else if (r < h0 + h1)          v = 1;
            else if (r < h0 + h1 + h2)     v = 2;
            else if (r < hotTot)           v = 3;
            else {
                // k-th smallest list value of this g (k 0-indexed), binary search
                int k = r - hotTot;        // 0 <= k < cg
                int loV = 4, hiV = MAXD2;
                while (loV < hiV) {
                    int mid = (loV + hiV) >> 1;
                    int c = 0;
                    for (int i = lane; i < nL; i += 64) {
                        int e = aload(&list[i]);
                        if ((e >> 16) == gg && (e & 0xFFFF) <= mid) c++;
                    }
                    #pragma unroll
                    for (int o = 1; o < 64; o <<= 1) c += __shfl_xor(c, o, 64);
                    if (c >= k + 1) hiV = mid; else loV = mid + 1;
                }
                v = loV;
            }
            sel[ri] = v;
        }
        if (lane == 0) {
            float a = sqrtf((float)sel[0]);
            float bv = sqrtf((float)sel[1]);
            float val = a + frac * (bv - a);
            atomicMax((int*)out + (gg >> 1), __float_as_int(val));  // val>=0
        }
    }
}

extern "C" void kernel_launch(void* const* d_in, const int* in_sizes, int n_in,
                              void* d_out, int out_size, void* d_ws, size_t ws_size,
                              hipStream_t stream)
{
    const float* pred = (const float*)d_in[0];
    const float* targ = (const float*)d_in[1];
    float* out = (float*)d_out;

    uint8_t* ws = (uint8_t*)d_ws;
    uint16_t* pb = (uint16_t*)ws;                    // NWORDS u16 (pred mask bits)
    uint16_t* tb = pb + NWORDS;                      // NWORDS u16 (targ mask bits)
    int* hot     = (int*)(tb + NWORDS);              // HOTN ints (d^2 = 0..3)
    int* done    = hot + HOTN;                       // 1 int
    int* listCnt = done + 1;                         // 1 int
    int* list    = listCnt + 1;                      // CAP ints (residual values)
    // bitpack zeroes [hot .. hot+ZEROINTS) = hot||done||listCnt

    bitpack_kernel<<<NWORDS/256, 256, 0, stream>>>(pred, targ, pb, tb, hot);
    edge_dist_hist<<<EGRID, 1024, 0, stream>>>(pb, tb, hot, done, listCnt, list, out);
}

// Round 20
// 27.292 us; speedup vs baseline: 1.1579x; 1.0152x over previous
//
#include <hip/hip_runtime.h>
#include <stdint.h>

#define BB 2
#define DD 64
#define HH 128
#define WW 128
#define NVOX (DD*HH*WW)        // 2^20 per batch
#define TOTAL (BB*NVOX)        // 2097152
#define NWORDS (TOTAL/16)      // 131072 uint16 mask words per volume
#define HOTN (4*8*4)           // 4 g x 8 slots x 4 hot bins
#define ZEROINTS (HOTN + 1 + 1)   // hot || done || listCnt  (130 ints)
#define EGRID (BB*DD*2)        // 256 blocks
#define CAP (1<<20)            // residual list capacity (value entries)
#define MAXD2 36227            // 63^2+127^2+127^2

__device__ __forceinline__ int aload(const int* p)
{
    return __hip_atomic_load(p, __ATOMIC_RELAXED, __HIP_MEMORY_SCOPE_AGENT);
}

// 4-bit spread: bit l -> bit 4l
__device__ __forceinline__ uint32_t spread4(uint32_t n)
{
    return (n & 1u) | ((n & 2u) << 3) | ((n & 4u) << 6) | ((n & 8u) << 9);
}

// ---------- bitpack: coalesced float4 load + wave-ballot pack --------------
// Thread gt loads pred4[gt], targ4[gt] (lane-contiguous). A wave covers 256
// consecutive voxels = 16 u16 words; 4 ballots collect the bits, lanes 0-15
// bit-interleave and store.
__global__ __launch_bounds__(256)
void bitpack_kernel(const float* __restrict__ pred, const float* __restrict__ targ,
                    uint16_t* __restrict__ pb, uint16_t* __restrict__ tb,
                    int* __restrict__ zint)
{
    int gt = blockIdx.x * 256 + threadIdx.x;       // 0..TOTAL/4-1
    if (gt < ZEROINTS) zint[gt] = 0;
    int lane = threadIdx.x & 63;
    int wbase = (gt & ~63) >> 2;                   // wave's first u16 word index

    const float4* srcs[2] = {(const float4*)pred, (const float4*)targ};
    uint16_t* dsts[2] = {pb, tb};
    #pragma unroll
    for (int s = 0; s < 2; ++s) {
        float4 f = srcs[s][gt];
        uint64_t B0 = __ballot(f.x > 0.5f);
        uint64_t B1 = __ballot(f.y > 0.5f);
        uint64_t B2 = __ballot(f.z > 0.5f);
        uint64_t B3 = __ballot(f.w > 0.5f);
        if (lane < 16) {
            uint32_t n0 = (uint32_t)(B0 >> (4 * lane)) & 0xFu;
            uint32_t n1 = (uint32_t)(B1 >> (4 * lane)) & 0xFu;
            uint32_t n2 = (uint32_t)(B2 >> (4 * lane)) & 0xFu;
            uint32_t n3 = (uint32_t)(B3 >> (4 * lane)) & 0xFu;
            uint32_t word = spread4(n0) | (spread4(n1) << 1)
                          | (spread4(n2) << 2) | (spread4(n3) << 3);
            dsts[s][wbase + lane] = (uint16_t)word;
        }
    }
}

// ---------- exact slow path (executed ~never; correctness fallback) --------
__device__ __forceinline__ int getbit(const uint16_t* __restrict__ M,
                                      int b, int z, int y, int x)
{
    return (M[(((size_t)(b * DD + z)) << 10) + (y << 3) + (x >> 4)] >> (x & 15)) & 1;
}

__device__ bool is_edge(const uint16_t* __restrict__ M, int b, int z, int y, int x)
{
    if (!getbit(M, b, z, y, x)) return false;
    if (x == 0 || x == WW-1 || y == 0 || y == HH-1 || z == 0 || z == DD-1) return true;
    int er = getbit(M,b,z,y,x-1) & getbit(M,b,z,y,x+1) &
             getbit(M,b,z,y-1,x) & getbit(M,b,z,y+1,x) &
             getbit(M,b,z-1,y,x) & getbit(M,b,z+1,y,x);
    return !er;
}

__device__ int slow_d2(const uint16_t* __restrict__ M, int b, int z, int y, int x)
{
    int best = 0x7FFFFFFF;
    for (int r = 2; r <= 127; ++r) {
        if (best <= r * r) break;
        for (int dz = -r; dz <= r; ++dz) {
            int zz = z + dz; if (zz < 0 || zz >= DD) continue;
            for (int dy = -r; dy <= r; ++dy) {
                int yy = y + dy; if (yy < 0 || yy >= HH) continue;
                int cheb = max(abs(dz), abs(dy));
                if (cheb == r) {
                    for (int dx = -r; dx <= r; ++dx) {
                        int xx = x + dx; if (xx < 0 || xx >= WW) continue;
                        if (is_edge(M, b, zz, yy, xx))
                            best = min(best, dz*dz + dy*dy + dx*dx);
                    }
                } else {
                    for (int t2 = 0; t2 < 2; ++t2) {
                        int dx = t2 ? r : -r;
                        int xx = x + dx; if (xx < 0 || xx >= WW) continue;
                        if (is_edge(M, b, zz, yy, xx))
                            best = min(best, dz*dz + dy*dy + dx*dx);
                    }
                }
            }
        }
    }
    return best;
}

// ---------- edges + word-parallel r<=1 distance + histogram + tail ---------
__global__ __launch_bounds__(1024)
void edge_dist_hist(const uint16_t* __restrict__ pb, const uint16_t* __restrict__ tb,
                    int* __restrict__ hot, int* __restrict__ done,
                    int* __restrict__ listCnt, int* __restrict__ list,
                    float* __restrict__ out)
{
    __shared__ uint16_t ownm[3][1024];   // own mask slices  z-1..z+1
    __shared__ uint16_t othm[5][1024];   // other mask slices z-2..z+2
    __shared__ uint16_t tedge[3][1024];  // other EDGE slices z-1..z+1
    __shared__ int lh[4];
    __shared__ int lastflag;
    int gid = blockIdx.x, tid = threadIdx.x;
    int dir = gid & 1;
    int bz  = gid >> 1;
    int b   = bz >> 6, z = bz & (DD - 1);
    const uint16_t* own = dir ? tb : pb;   // dir0: E = pred edges
    const uint16_t* oth = dir ? pb : tb;   // dir0: distances to targ edges

    {   // cooperative load: 8 slices x 1024 words (zero out-of-range slices)
        int s = tid >> 7, off = (tid & 127) * 8;
        int zs = (s < 3) ? z + s - 1 : z + s - 5;
        const uint16_t* src = (s < 3) ? own : oth;
        uint16_t* dst = (s < 3) ? &ownm[s][off] : &othm[s - 3][off];
        if (zs >= 0 && zs < DD)
            *(uint4*)dst = *(const uint4*)(src + (((size_t)(b * DD + zs)) << 10) + off);
        else
            *(uint4*)dst = make_uint4(0, 0, 0, 0);
    }
    if (tid < 4) lh[tid] = 0;
    __syncthreads();

    int w = tid, y = w >> 3, wx = w & 7;

    // phase A: other-surface edge words for dz in {-1,0,1}
    #pragma unroll
    for (int dzi = 0; dzi < 3; ++dzi) {
        uint32_t c = othm[dzi + 1][w];
        uint32_t l = wx > 0 ? othm[dzi + 1][w - 1] : 0;
        uint32_t r = wx < 7 ? othm[dzi + 1][w + 1] : 0;
        uint32_t ext = (l >> 15) | (c << 1) | ((r & 1u) << 17);
        uint32_t m = (ext >> 1) & 0xFFFFu, L = ext & 0xFFFFu, R = (ext >> 2) & 0xFFFFu;
        uint32_t ym = y > 0   ? othm[dzi + 1][w - 8] : 0;
        uint32_t yp = y < 127 ? othm[dzi + 1][w + 8] : 0;
        uint32_t zm = othm[dzi][w], zp = othm[dzi + 2][w];
        uint32_t er = m & L & R & ym & yp & zm & zp;
        tedge[dzi][w] = (uint16_t)(m & ~er);
    }

    // E: own-surface edge word
    uint32_t E;
    {
        uint32_t c = ownm[1][w];
        uint32_t l = wx > 0 ? ownm[1][w - 1] : 0;
        uint32_t r = wx < 7 ? ownm[1][w + 1] : 0;
        uint32_t ext = (l >> 15) | (c << 1) | ((r & 1u) << 17);
        uint32_t m = (ext >> 1) & 0xFFFFu, L = ext & 0xFFFFu, R = (ext >> 2) & 0xFFFFu;
        uint32_t ym = y > 0   ? ownm[1][w - 8] : 0;
        uint32_t yp = y < 127 ? ownm[1][w + 8] : 0;
        uint32_t zm = ownm[0][w], zp = ownm[2][w];
        E = m & ~(m & L & R & ym & yp & zm & zp);
    }
    __syncthreads();   // tedge ready

    // phase B: M0..M3 (has oth-edge at d^2=0/1/2/3) from tedge ext rows
    uint32_t M0 = 0, M1 = 0, M2 = 0, M3 = 0;
    #pragma unroll
    for (int dzi = 0; dzi < 3; ++dzi) {
        #pragma unroll
        for (int dyy = -1; dyy <= 1; ++dyy) {
            int yy = y + dyy;
            uint32_t c = 0, l = 0, r = 0;
            if (yy >= 0 && yy < HH) {
                int w2 = (yy << 3) + wx;
                c = tedge[dzi][w2];
                l = wx > 0 ? tedge[dzi][w2 - 1] : 0;
                r = wx < 7 ? tedge[dzi][w2 + 1] : 0;
            }
            uint32_t ext = (l >> 15) | (c << 1) | ((r & 1u) << 17);
            uint32_t s0 = (ext >> 1) & 0xFFFFu;                      // dx = 0
            uint32_t s1 = (ext & 0xFFFFu) | ((ext >> 2) & 0xFFFFu);  // dx = +-1
            int a = (dzi == 1 ? 0 : 1) + (dyy == 0 ? 0 : 1);
            if (a == 0)      { M0 |= s0; M1 |= s1; }
            else if (a == 1) { M1 |= s0; M2 |= s1; }
            else             { M2 |= s0; M3 |= s1; }
        }
    }

    uint32_t rem = E;
    int c0 = __popc(rem & M0); rem &= ~M0;
    int c1 = __popc(rem & M1); rem &= ~M1;
    int c2 = __popc(rem & M2); rem &= ~M2;
    int c3 = __popc(rem & M3); rem &= ~M3;

    int g = b * 2 + dir;

    // slow path for residual bits (expected ~0 voxels total): append VALUE
    while (rem) {
        int i = __builtin_ctz(rem); rem &= rem - 1;
        int d2 = slow_d2(oth, b, z, y, wx * 16 + i);   // always >= 4
        if (d2 > MAXD2) d2 = MAXD2;
        int pos = atomicAdd(listCnt, 1);
        if (pos < CAP)
            __hip_atomic_store(&list[pos], (g << 16) | d2,
                               __ATOMIC_RELEASE, __HIP_MEMORY_SCOPE_AGENT);
    }

    // wave reduce the 4 hot counters, then one LDS atomic per wave
    int lane = tid & 63;
    #pragma unroll
    for (int o = 1; o < 64; o <<= 1) {
        c0 += __shfl_xor(c0, o, 64);
        c1 += __shfl_xor(c1, o, 64);
        c2 += __shfl_xor(c2, o, 64);
        c3 += __shfl_xor(c3, o, 64);
    }
    if (lane == 0) {
        if (c0) atomicAdd(&lh[0], c0);
        if (c1) atomicAdd(&lh[1], c1);
        if (c2) atomicAdd(&lh[2], c2);
        if (c3) atomicAdd(&lh[3], c3);
    }
    __syncthreads();
    if (tid < 4) {
        int v = lh[tid];
        int slot = bz & 7;             // spread global flush across 8 shadows
        if (v) atomicAdd(&hot[(g * 8 + slot) * 4 + tid], v);
    }
    // drain this block's flush atomics (syncthreads implies vmcnt(0) per wave)
    __syncthreads();
    if (tid == 0) {
        int old = __hip_atomic_fetch_add(done, 1, __ATOMIC_RELAXED,
                                         __HIP_MEMORY_SCOPE_AGENT);
        lastflag = (old == EGRID - 1);
    }
    __syncthreads();
    if (!lastflag) return;

    // ------------- last block only: percentile (wave w handles g=w) -------
    if (tid >= 256) return;
    {
        int gg = tid >> 6;
        int nL = aload(listCnt); if (nL > CAP) nL = CAP;

        // hot totals for this g (lanes 0..3 gather, then broadcast)
        int cb = 0;
        if (lane < 4) {
            #pragma unroll
            for (int s = 0; s < 8; ++s) cb += aload(&hot[(gg * 8 + s) * 4 + lane]);
        }
        int h0 = __shfl(cb, 0, 64), h1 = __shfl(cb, 1, 64);
        int h2 = __shfl(cb, 2, 64), h3 = __shfl(cb, 3, 64);

        // count of this g's list entries (wave-uniform after reduce)
        int cg = 0;
        for (int i = lane; i < nL; i += 64) {
            int e = aload(&list[i]);
            if ((e >> 16) == gg) cg++;
        }
        #pragma unroll
        for (int o = 1; o < 64; o <<= 1) cg += __shfl_xor(cg, o, 64);

        int n = h0 + h1 + h2 + h3 + cg;
        int hotTot = n - cg;

        float pos = 0.95f * (float)(n - 1);
        float fpos = floorf(pos);
        int lo = (int)fpos;
        int nm1 = n - 1; if (nm1 < 0) nm1 = 0;
        if (lo < 0) lo = 0;
        if (lo > nm1) lo = nm1;
        int hi = lo + 1; if (hi > nm1) hi = nm1;
        float frac = pos - fpos;

        int sel[2]; int ranks[2] = {lo, hi};
        #pragma unroll
        for (int ri = 0; ri < 2; ++ri) {
            int r = ranks[ri];
            int v;
            if      (r < h0)               v = 0;
            else if (r < h0 + h1)          v = 1;
            else if (r < h0 + h1 + h2)     v = 2;
            else if (r < hotTot)           v = 3;
            else {
                // k-th smallest list value of this g (k 0-indexed), binary search
                int k = r - hotTot;        // 0 <= k < cg
                int loV = 4, hiV = MAXD2;
                while (loV < hiV) {
                    int mid = (loV + hiV) >> 1;
                    int c = 0;
                    for (int i = lane; i < nL; i += 64) {
                        int e = aload(&list[i]);
                        if ((e >> 16) == gg && (e & 0xFFFF) <= mid) c++;
                    }
                    #pragma unroll
                    for (int o = 1; o < 64; o <<= 1) c += __shfl_xor(c, o, 64);
                    if (c >= k + 1) hiV = mid; else loV = mid + 1;
                }
                v = loV;
            }
            sel[ri] = v;
        }
        if (lane == 0) {
            float a = sqrtf((float)sel[0]);
            float bv = sqrtf((float)sel[1]);
            float val = a + frac * (bv - a);
            atomicMax((int*)out + (gg >> 1), __float_as_int(val));  // val>=0
        }
    }
}

extern "C" void kernel_launch(void* const* d_in, const int* in_sizes, int n_in,
                              void* d_out, int out_size, void* d_ws, size_t ws_size,
                              hipStream_t stream)
{
    const float* pred = (const float*)d_in[0];
    const float* targ = (const float*)d_in[1];
    float* out = (float*)d_out;

    uint8_t* ws = (uint8_t*)d_ws;
    uint16_t* pb = (uint16_t*)ws;                    // NWORDS u16 (pred mask bits)
    uint16_t* tb = pb + NWORDS;                      // NWORDS u16 (targ mask bits)
    int* hot     = (int*)(tb + NWORDS);              // HOTN ints (d^2 = 0..3)
    int* done    = hot + HOTN;                       // 1 int
    int* listCnt = done + 1;                         // 1 int
    int* list    = listCnt + 1;                      // CAP ints (residual values)
    // bitpack zeroes [hot .. hot+ZEROINTS) = hot||done||listCnt

    bitpack_kernel<<<(TOTAL/4)/256, 256, 0, stream>>>(pred, targ, pb, tb, hot);
    edge_dist_hist<<<EGRID, 1024, 0, stream>>>(pb, tb, hot, done, listCnt, list, out);
}

// Round 21
// 20.692 us; speedup vs baseline: 1.5271x; 1.3189x over previous
//
#include <hip/hip_runtime.h>
#include <stdint.h>

#define BB 2
#define DD 64
#define HH 128
#define WW 128
#define NVOX (DD*HH*WW)        // 2^20 per batch
#define TOTAL (BB*NVOX)        // 2097152
#define NWORDS (TOTAL/16)      // 131072 uint16 mask words per volume
#define HOTN (4*8*4)           // 4 g x 8 slots x 4 hot bins
#define ZEROINTS (HOTN + 1 + 1)   // hot || done || listCnt  (130 ints)
#define EGRID (BB*DD*2)        // 256 blocks
#define CAP (1<<20)            // residual list capacity
#define MAXD2 36227            // 63^2+127^2+127^2
#define INF_I 0x7FFFFFFF

__device__ __forceinline__ int aload(const int* p)
{
    return __hip_atomic_load(p, __ATOMIC_RELAXED, __HIP_MEMORY_SCOPE_AGENT);
}

// 4-bit spread: bit l -> bit 4l
__device__ __forceinline__ uint32_t spread4(uint32_t n)
{
    return (n & 1u) | ((n & 2u) << 3) | ((n & 4u) << 6) | ((n & 8u) << 9);
}

// ---------- bitpack: coalesced float4 load + wave-ballot pack --------------
__global__ __launch_bounds__(256)
void bitpack_kernel(const float* __restrict__ pred, const float* __restrict__ targ,
                    uint16_t* __restrict__ pb, uint16_t* __restrict__ tb,
                    int* __restrict__ zint)
{
    int gt = blockIdx.x * 256 + threadIdx.x;       // 0..TOTAL/4-1
    if (gt < ZEROINTS) zint[gt] = 0;
    int lane = threadIdx.x & 63;
    int wbase = (gt & ~63) >> 2;                   // wave's first u16 word index

    const float4* srcs[2] = {(const float4*)pred, (const float4*)targ};
    uint16_t* dsts[2] = {pb, tb};
    #pragma unroll
    for (int s = 0; s < 2; ++s) {
        float4 f = srcs[s][gt];
        uint64_t B0 = __ballot(f.x > 0.5f);
        uint64_t B1 = __ballot(f.y > 0.5f);
        uint64_t B2 = __ballot(f.z > 0.5f);
        uint64_t B3 = __ballot(f.w > 0.5f);
        if (lane < 16) {
            uint32_t n0 = (uint32_t)(B0 >> (4 * lane)) & 0xFu;
            uint32_t n1 = (uint32_t)(B1 >> (4 * lane)) & 0xFu;
            uint32_t n2 = (uint32_t)(B2 >> (4 * lane)) & 0xFu;
            uint32_t n3 = (uint32_t)(B3 >> (4 * lane)) & 0xFu;
            uint32_t word = spread4(n0) | (spread4(n1) << 1)
                          | (spread4(n2) << 2) | (spread4(n3) << 3);
            dsts[s][wbase + lane] = (uint16_t)word;
        }
    }
}

// ---------- bit-volume helpers for residual resolve (tail only) ------------
__device__ __forceinline__ int getbit(const uint16_t* __restrict__ M,
                                      int b, int z, int y, int x)
{
    return (M[(((size_t)(b * DD + z)) << 10) + (y << 3) + (x >> 4)] >> (x & 15)) & 1;
}

__device__ bool is_edge(const uint16_t* __restrict__ M, int b, int z, int y, int x)
{
    if (!getbit(M, b, z, y, x)) return false;
    if (x == 0 || x == WW-1 || y == 0 || y == HH-1 || z == 0 || z == DD-1) return true;
    int er = getbit(M,b,z,y,x-1) & getbit(M,b,z,y,x+1) &
             getbit(M,b,z,y-1,x) & getbit(M,b,z,y+1,x) &
             getbit(M,b,z-1,y,x) & getbit(M,b,z+1,y,x);
    return !er;
}

// ---------- edges + word-parallel r<=1 distance + histogram + tail ---------
__global__ __launch_bounds__(1024)
void edge_dist_hist(const uint16_t* __restrict__ pb, const uint16_t* __restrict__ tb,
                    int* __restrict__ hot, int* __restrict__ done,
                    int* __restrict__ listCnt, int* __restrict__ list,
                    float* __restrict__ out)
{
    __shared__ uint16_t ownm[3][1024];   // own mask slices  z-1..z+1
    __shared__ uint16_t othm[5][1024];   // other mask slices z-2..z+2
    __shared__ uint16_t tedge[3][1024];  // other EDGE slices z-1..z+1
    __shared__ int lh[4];
    __shared__ int lastflag;
    int gid = blockIdx.x, tid = threadIdx.x;
    int dir = gid & 1;
    int bz  = gid >> 1;
    int b   = bz >> 6, z = bz & (DD - 1);
    const uint16_t* own = dir ? tb : pb;   // dir0: E = pred edges
    const uint16_t* oth = dir ? pb : tb;   // dir0: distances to targ edges

    {   // cooperative load: 8 slices x 1024 words (zero out-of-range slices)
        int s = tid >> 7, off = (tid & 127) * 8;
        int zs = (s < 3) ? z + s - 1 : z + s - 5;
        const uint16_t* src = (s < 3) ? own : oth;
        uint16_t* dst = (s < 3) ? &ownm[s][off] : &othm[s - 3][off];
        if (zs >= 0 && zs < DD)
            *(uint4*)dst = *(const uint4*)(src + (((size_t)(b * DD + zs)) << 10) + off);
        else
            *(uint4*)dst = make_uint4(0, 0, 0, 0);
    }
    if (tid < 4) lh[tid] = 0;
    __syncthreads();

    int w = tid, y = w >> 3, wx = w & 7;

    // phase A: other-surface edge words for dz in {-1,0,1}
    #pragma unroll
    for (int dzi = 0; dzi < 3; ++dzi) {
        uint32_t c = othm[dzi + 1][w];
        uint32_t l = wx > 0 ? othm[dzi + 1][w - 1] : 0;
        uint32_t r = wx < 7 ? othm[dzi + 1][w + 1] : 0;
        uint32_t ext = (l >> 15) | (c << 1) | ((r & 1u) << 17);
        uint32_t m = (ext >> 1) & 0xFFFFu, L = ext & 0xFFFFu, R = (ext >> 2) & 0xFFFFu;
        uint32_t ym = y > 0   ? othm[dzi + 1][w - 8] : 0;
        uint32_t yp = y < 127 ? othm[dzi + 1][w + 8] : 0;
        uint32_t zm = othm[dzi][w], zp = othm[dzi + 2][w];
        uint32_t er = m & L & R & ym & yp & zm & zp;
        tedge[dzi][w] = (uint16_t)(m & ~er);
    }

    // E: own-surface edge word
    uint32_t E;
    {
        uint32_t c = ownm[1][w];
        uint32_t l = wx > 0 ? ownm[1][w - 1] : 0;
        uint32_t r = wx < 7 ? ownm[1][w + 1] : 0;
        uint32_t ext = (l >> 15) | (c << 1) | ((r & 1u) << 17);
        uint32_t m = (ext >> 1) & 0xFFFFu, L = ext & 0xFFFFu, R = (ext >> 2) & 0xFFFFu;
        uint32_t ym = y > 0   ? ownm[1][w - 8] : 0;
        uint32_t yp = y < 127 ? ownm[1][w + 8] : 0;
        uint32_t zm = ownm[0][w], zp = ownm[2][w];
        E = m & ~(m & L & R & ym & yp & zm & zp);
    }
    __syncthreads();   // tedge ready

    // phase B: M0..M3 (has oth-edge at d^2=0/1/2/3) from tedge ext rows
    uint32_t M0 = 0, M1 = 0, M2 = 0, M3 = 0;
    #pragma unroll
    for (int dzi = 0; dzi < 3; ++dzi) {
        #pragma unroll
        for (int dyy = -1; dyy <= 1; ++dyy) {
            int yy = y + dyy;
            uint32_t c = 0, l = 0, r = 0;
            if (yy >= 0 && yy < HH) {
                int w2 = (yy << 3) + wx;
                c = tedge[dzi][w2];
                l = wx > 0 ? tedge[dzi][w2 - 1] : 0;
                r = wx < 7 ? tedge[dzi][w2 + 1] : 0;
            }
            uint32_t ext = (l >> 15) | (c << 1) | ((r & 1u) << 17);
            uint32_t s0 = (ext >> 1) & 0xFFFFu;                      // dx = 0
            uint32_t s1 = (ext & 0xFFFFu) | ((ext >> 2) & 0xFFFFu);  // dx = +-1
            int a = (dzi == 1 ? 0 : 1) + (dyy == 0 ? 0 : 1);
            if (a == 0)      { M0 |= s0; M1 |= s1; }
            else if (a == 1) { M1 |= s0; M2 |= s1; }
            else             { M2 |= s0; M3 |= s1; }
        }
    }

    uint32_t rem = E;
    int c0 = __popc(rem & M0); rem &= ~M0;
    int c1 = __popc(rem & M1); rem &= ~M1;
    int c2 = __popc(rem & M2); rem &= ~M2;
    int c3 = __popc(rem & M3); rem &= ~M3;

    int g = b * 2 + dir;

    // residual voxels (expected ~2-4, boundary-clipped cubes): append POSITION
    // only — NO serial distance scan in the hot path (it was the straggler).
    while (rem) {
        int i = __builtin_ctz(rem); rem &= rem - 1;
        int x = wx * 16 + i;
        int pos = atomicAdd(listCnt, 1);
        if (pos < CAP)
            __hip_atomic_store(&list[pos], g | (z << 2) | (y << 8) | (x << 15),
                               __ATOMIC_RELEASE, __HIP_MEMORY_SCOPE_AGENT);
    }

    // wave reduce the 4 hot counters, then one LDS atomic per wave
    int lane = tid & 63;
    #pragma unroll
    for (int o = 1; o < 64; o <<= 1) {
        c0 += __shfl_xor(c0, o, 64);
        c1 += __shfl_xor(c1, o, 64);
        c2 += __shfl_xor(c2, o, 64);
        c3 += __shfl_xor(c3, o, 64);
    }
    if (lane == 0) {
        if (c0) atomicAdd(&lh[0], c0);
        if (c1) atomicAdd(&lh[1], c1);
        if (c2) atomicAdd(&lh[2], c2);
        if (c3) atomicAdd(&lh[3], c3);
    }
    __syncthreads();
    if (tid < 4) {
        int v = lh[tid];
        int slot = bz & 7;             // spread global flush across 8 shadows
        if (v) atomicAdd(&hot[(g * 8 + slot) * 4 + tid], v);
    }
    // drain this block's flush atomics (syncthreads implies vmcnt(0) per wave)
    __syncthreads();
    if (tid == 0) {
        int old = __hip_atomic_fetch_add(done, 1, __ATOMIC_RELAXED,
                                         __HIP_MEMORY_SCOPE_AGENT);
        lastflag = (old == EGRID - 1);
    }
    __syncthreads();
    if (!lastflag) return;

    // ------------- last block only: resolve residuals + percentile --------
    if (tid >= 256) return;
    int nL = aload(listCnt); if (nL > CAP) nL = CAP;
    int wv = tid >> 6;                 // wave id 0..3

    // resolve each residual with a WAVE-PARALLEL expanding-shell scan
    for (int idx = wv; idx < nL; idx += 4) {
        int e = aload(&list[idx]);
        int g2 = e & 3, zz0 = (e >> 2) & 63, yy0 = (e >> 8) & 127, xx0 = (e >> 15) & 127;
        const uint16_t* M = (g2 & 1) ? pb : tb;   // oth volume for this g
        int bb = g2 >> 1;
        int best = INF_I;
        for (int r = 2; r <= 127; ++r) {
            if (best <= r * r) break;
            int side = 2 * r + 1, npts = side * side * side;
            int lmin = INF_I;
            for (int k = lane; k < npts; k += 64) {
                int dzz = k / (side * side) - r;
                int r2  = k % (side * side);
                int dyy = r2 / side - r;
                int dxx = r2 % side - r;
                int cheb = max(abs(dzz), max(abs(dyy), abs(dxx)));
                if (cheb != r) continue;
                int zz = zz0 + dzz, yy = yy0 + dyy, xx = xx0 + dxx;
                if (zz < 0 || zz >= DD || yy < 0 || yy >= HH || xx < 0 || xx >= WW) continue;
                if (is_edge(M, bb, zz, yy, xx))
                    lmin = min(lmin, dzz*dzz + dyy*dyy + dxx*dxx);
            }
            #pragma unroll
            for (int o = 1; o < 64; o <<= 1) lmin = min(lmin, __shfl_xor(lmin, o, 64));
            best = min(best, lmin);
        }
        if (best > MAXD2) best = MAXD2;
        if (lane == 0)
            __hip_atomic_store(&list[idx], (g2 << 16) | best,
                               __ATOMIC_RELEASE, __HIP_MEMORY_SCOPE_AGENT);
    }
    __syncthreads();

    {
        int gg = wv;

        // hot totals for this g (lanes 0..3 gather, then broadcast)
        int cb = 0;
        if (lane < 4) {
            #pragma unroll
            for (int s = 0; s < 8; ++s) cb += aload(&hot[(gg * 8 + s) * 4 + lane]);
        }
        int h0 = __shfl(cb, 0, 64), h1 = __shfl(cb, 1, 64);
        int h2 = __shfl(cb, 2, 64), h3 = __shfl(cb, 3, 64);

        // count of this g's list entries (wave-uniform after reduce)
        int cg = 0;
        for (int i = lane; i < nL; i += 64) {
            int e = aload(&list[i]);
            if ((e >> 16) == gg) cg++;
        }
        #pragma unroll
        for (int o = 1; o < 64; o <<= 1) cg += __shfl_xor(cg, o, 64);

        int n = h0 + h1 + h2 + h3 + cg;
        int hotTot = n - cg;

        float pos = 0.95f * (float)(n - 1);
        float fpos = floorf(pos);
        int lo = (int)fpos;
        int nm1 = n - 1; if (nm1 < 0) nm1 = 0;
        if (lo < 0) lo = 0;
        if (lo > nm1) lo = nm1;
        int hi = lo + 1; if (hi > nm1) hi = nm1;
        float frac = pos - fpos;

        int sel[2]; int ranks[2] = {lo, hi};
        #pragma unroll
        for (int ri = 0; ri < 2; ++ri) {
            int r = ranks[ri];
            int v;
            if      (r < h0)               v = 0;
            else if (r < h0 + h1)          v = 1;
            else if (r < h0 + h1 + h2)     v = 2;
            else if (r < hotTot)           v = 3;
            else {
                // k-th smallest list value of this g, binary search over values
                int k = r - hotTot;        // 0 <= k < cg
                int loV = 4, hiV = MAXD2;
                while (loV < hiV) {
                    int mid = (loV + hiV) >> 1;
                    int c = 0;
                    for (int i = lane; i < nL; i += 64) {
                        int e = aload(&list[i]);
                        if ((e >> 16) == gg && (e & 0xFFFF) <= mid) c++;
                    }
                    #pragma unroll
                    for (int o = 1; o < 64; o <<= 1) c += __shfl_xor(c, o, 64);
                    if (c >= k + 1) hiV = mid; else loV = mid + 1;
                }
                v = loV;
            }
            sel[ri] = v;
        }
        if (lane == 0) {
            float a = sqrtf((float)sel[0]);
            float bv = sqrtf((float)sel[1]);
            float val = a + frac * (bv - a);
            atomicMax((int*)out + (gg >> 1), __float_as_int(val));  // val>=0
        }
    }
}

extern "C" void kernel_launch(void* const* d_in, const int* in_sizes, int n_in,
                              void* d_out, int out_size, void* d_ws, size_t ws_size,
                              hipStream_t stream)
{
    const float* pred = (const float*)d_in[0];
    const float* targ = (const float*)d_in[1];
    float* out = (float*)d_out;

    uint8_t* ws = (uint8_t*)d_ws;
    uint16_t* pb = (uint16_t*)ws;                    // NWORDS u16 (pred mask bits)
    uint16_t* tb = pb + NWORDS;                      // NWORDS u16 (targ mask bits)
    int* hot     = (int*)(tb + NWORDS);              // HOTN ints (d^2 = 0..3)
    int* done    = hot + HOTN;                       // 1 int
    int* listCnt = done + 1;                         // 1 int
    int* list    = listCnt + 1;                      // CAP ints (residuals)
    // bitpack zeroes [hot .. hot+ZEROINTS) = hot||done||listCnt

    bitpack_kernel<<<(TOTAL/4)/256, 256, 0, stream>>>(pred, targ, pb, tb, hot);
    edge_dist_hist<<<EGRID, 1024, 0, stream>>>(pb, tb, hot, done, listCnt, list, out);
}